// Round 1
// baseline (246.000 us; speedup 1.0000x reference)
//
#include <hip/hip_runtime.h>
#include <stdint.h>

// FlatCritic: B=128, L=512, D_DESC=768, D_STD=128, D_ACT=128, D_CTX=1152, H=512
// out = [q (B*L f32), emb (B*L*128 f32)]

typedef __attribute__((ext_vector_type(8))) short short8_t;
typedef __attribute__((ext_vector_type(4))) short short4_t;
typedef __attribute__((ext_vector_type(4))) float f32x4;

__device__ inline unsigned short f2bf(float f) {
  union { float f; unsigned u; } v; v.f = f;
  unsigned r = v.u + 0x7FFFu + ((v.u >> 16) & 1u);
  return (unsigned short)(r >> 16);
}

// ---------------- prep: transpose weights to bf16 [N][K] layouts in ws ----------------
__global__ __launch_bounds__(256) void prep_weights(
    const float* __restrict__ Wd, const float* __restrict__ Ws,
    const float* __restrict__ W1, const float* __restrict__ W2,
    unsigned short* __restrict__ wdT, unsigned short* __restrict__ wsT,
    unsigned short* __restrict__ w1eT, unsigned short* __restrict__ w2T) {
  int i = blockIdx.x * blockDim.x + threadIdx.x;
  int n = blockDim.x * gridDim.x;
  for (int idx = i; idx < 128 * 768; idx += n) { int c = idx / 768, d = idx % 768; wdT[idx] = f2bf(Wd[d * 128 + c]); }
  for (int idx = i; idx < 128 * 128; idx += n) { int c = idx / 128, d = idx % 128; wsT[idx] = f2bf(Ws[d * 128 + c]); }
  for (int idx = i; idx < 512 * 128; idx += n) { int c = idx / 128, k = idx % 128; w1eT[idx] = f2bf(W1[(size_t)(1152 + k) * 512 + c]); }
  for (int idx = i; idx < 512 * 512; idx += n) { int c = idx / 512, k = idx % 512; w2T[idx] = f2bf(W2[(size_t)k * 512 + c]); }
}

// ---------------- cc[b][h] = b1[h] + ctx(b) . W1[:1152, h]  (fp32 exact) ----------------
__global__ __launch_bounds__(256) void ctx_cc(
    const float* __restrict__ instr, const float* __restrict__ state, const float* __restrict__ hidden,
    const float* __restrict__ W1, const float* __restrict__ b1, float* __restrict__ cc) {
  int bid = blockIdx.x;
  int b = bid >> 2, part = bid & 3;
  __shared__ float ctx[1152];
  __shared__ float red[256];
  int t = threadIdx.x;
  for (int i = t; i < 512; i += 256) { ctx[i] = instr[b * 512 + i]; ctx[512 + i] = state[b * 512 + i]; }
  if (t < 128) ctx[1024 + t] = hidden[b * 128 + t];
  __syncthreads();
  int hcol = part * 128 + (t & 127);
  int half = t >> 7;
  float acc = 0.f;
  const float* wp = W1 + (size_t)half * 576 * 512 + hcol;
  #pragma unroll 8
  for (int d = 0; d < 576; ++d) acc = fmaf(ctx[half * 576 + d], wp[(size_t)d * 512], acc);
  red[t] = acc;
  __syncthreads();
  if (t < 128) cc[b * 512 + hcol] = red[t] + red[t + 128] + b1[hcol];
}

// ---------------- q_inv[b]: MLP tail on emb=0 rows ----------------
__global__ __launch_bounds__(256) void qinv_kernel(
    const float* __restrict__ cc, const float* __restrict__ W2, const float* __restrict__ b2,
    const float* __restrict__ W3, const float* __restrict__ b3, float* __restrict__ qinv) {
  int b = blockIdx.x, t = threadIdx.x;
  __shared__ float h1s[512];
  __shared__ float red[256];
  for (int i = t; i < 512; i += 256) h1s[i] = fmaxf(cc[b * 512 + i], 0.f);
  __syncthreads();
  float a0 = b2[t], a1 = b2[t + 256];
  #pragma unroll 4
  for (int c = 0; c < 512; ++c) {
    float x = h1s[c];
    a0 = fmaf(x, W2[(size_t)c * 512 + t], a0);
    a1 = fmaf(x, W2[(size_t)c * 512 + t + 256], a1);
  }
  red[t] = fmaxf(a0, 0.f) * W3[t] + fmaxf(a1, 0.f) * W3[t + 256];
  __syncthreads();
  for (int s = 128; s > 0; s >>= 1) { if (t < s) red[t] += red[t + s]; __syncthreads(); }
  if (t == 0) qinv[b] = fmaxf(red[0] + b3[0], 0.f);
}

// ---------------- main: per-(b, 64-row tile) fused proj + MLP ----------------
__global__ __launch_bounds__(256) void flatcritic_main(
    const float* __restrict__ adesc, const float* __restrict__ astd,
    const int* __restrict__ type_ids, const int* __restrict__ lengths,
    const float* __restrict__ bdesc, const float* __restrict__ bstd,
    const float* __restrict__ b2, const float* __restrict__ W3, const float* __restrict__ b3,
    const unsigned short* __restrict__ wdT, const unsigned short* __restrict__ wsT,
    const unsigned short* __restrict__ w1eT, const unsigned short* __restrict__ w2T,
    const float* __restrict__ cc, const float* __restrict__ qinv,
    float* __restrict__ qout, float* __restrict__ embout) {
  int b = blockIdx.y, lt = blockIdx.x;
  int l0 = lt * 64;
  int t = threadIdx.x;
  int len = lengths[b];
  int nv = len - l0; nv = nv < 0 ? 0 : (nv > 64 ? 64 : nv);
  f32x4 zero4 = {0.f, 0.f, 0.f, 0.f};

  if (nv == 0) {  // fully-invalid tile: q = q_inv, emb = 0
    float qv = qinv[b];
    if (t < 64) qout[(size_t)b * 512 + l0 + t] = qv;
    float* ep = embout + (size_t)(b * 512 + l0) * 128;
    for (int i = t; i < 2048; i += 256) ((f32x4*)ep)[i] = zero4;
    return;
  }

  __shared__ unsigned short ldsA[64 * 520];  // action chunks during P; H1 (row-major, pad 8) after S1
  __shared__ unsigned short ldsE[64 * 136];  // emb bf16 row-major (pad 8)
  __shared__ unsigned short ldsW[512 * 40];  // weight chunks: [128][136] in P, [512][40] in S1/S2
  __shared__ int typeL[64];
  __shared__ float qpart[4][64];

  int w = t >> 6, l = t & 63, g = l >> 4, ln = l & 15;

  if (t < 64) typeL[t] = type_ids[b * 512 + l0 + t];
  __syncthreads();

  // ===== Stage P: embT[k][r] = sum_d WT[k][d] * actT[d][r]  (zero-masked per type/validity)
  f32x4 embacc[2][4];
  #pragma unroll
  for (int mb = 0; mb < 2; ++mb)
    #pragma unroll
    for (int nb = 0; nb < 4; ++nb) embacc[mb][nb] = zero4;

  const float* descB = adesc + (size_t)(b * 512 + l0) * 768;
  const float* stdB  = astd  + (size_t)(b * 512 + l0) * 128;

  for (int kc = 0; kc < 7; ++kc) {  // 0..5: desc 128-K chunks; 6: std chunk
    bool isStd = (kc == 6);
    // stage action chunk [64][128] f32 -> bf16 into ldsA[64][136]
    #pragma unroll
    for (int i = 0; i < 8; ++i) {
      int u = t + i * 256;
      int r = u >> 5, c4 = u & 31;
      bool ok = (r < nv) && ((typeL[r] == 0) != isStd);
      f32x4 v = zero4;
      if (ok) v = isStd ? *(const f32x4*)(stdB + (size_t)r * 128 + c4 * 4)
                        : *(const f32x4*)(descB + (size_t)r * 768 + kc * 128 + c4 * 4);
      short4_t p; p[0] = (short)f2bf(v[0]); p[1] = (short)f2bf(v[1]); p[2] = (short)f2bf(v[2]); p[3] = (short)f2bf(v[3]);
      *(short4_t*)&ldsA[r * 136 + c4 * 4] = p;
    }
    // stage weight chunk [128][128] bf16 -> ldsW[128][136]
    const unsigned short* wsrc = isStd ? wsT : (wdT + kc * 128);
    int wstride = isStd ? 128 : 768;
    #pragma unroll
    for (int i = 0; i < 8; ++i) {
      int u = t + i * 256;
      int c = u >> 4, s8 = u & 15;
      *(short8_t*)&ldsW[c * 136 + s8 * 8] = *(const short8_t*)(wsrc + (size_t)c * wstride + s8 * 8);
    }
    __syncthreads();
    #pragma unroll
    for (int ks = 0; ks < 4; ++ks) {
      short8_t a0 = *(short8_t*)&ldsW[((2 * w + 0) * 16 + ln) * 136 + ks * 32 + g * 8];
      short8_t a1 = *(short8_t*)&ldsW[((2 * w + 1) * 16 + ln) * 136 + ks * 32 + g * 8];
      #pragma unroll
      for (int nb = 0; nb < 4; ++nb) {
        short8_t bb = *(short8_t*)&ldsA[(nb * 16 + ln) * 136 + ks * 32 + g * 8];
        embacc[0][nb] = __builtin_amdgcn_mfma_f32_16x16x32_bf16(a0, bb, embacc[0][nb], 0, 0, 0);
        embacc[1][nb] = __builtin_amdgcn_mfma_f32_16x16x32_bf16(a1, bb, embacc[1][nb], 0, 0, 0);
      }
    }
    __syncthreads();
  }

  // bias (masked) + write emb f32 global + bf16 -> ldsE
  #pragma unroll
  for (int mb = 0; mb < 2; ++mb) {
    int k0 = (2 * w + mb) * 16 + g * 4;
    f32x4 bd4 = *(const f32x4*)(bdesc + k0);
    f32x4 bs4 = *(const f32x4*)(bstd + k0);
    #pragma unroll
    for (int nb = 0; nb < 4; ++nb) {
      int r = nb * 16 + ln;
      f32x4 e = embacc[mb][nb];
      if (r < nv) { f32x4 bias = (typeL[r] == 0) ? bd4 : bs4; e = e + bias; }
      else e = zero4;
      *(f32x4*)(embout + (size_t)(b * 512 + l0 + r) * 128 + k0) = e;
      short4_t p; p[0] = (short)f2bf(e[0]); p[1] = (short)f2bf(e[1]); p[2] = (short)f2bf(e[2]); p[3] = (short)f2bf(e[3]);
      *(short4_t*)&ldsE[r * 136 + k0] = p;
    }
  }
  __syncthreads();

  // ===== Stage 1: H1T[c][r] = cc[b][c] + sum_k w1eT[c][k]*embT[k][r], relu -> ldsA[64][520]
  f32x4 acc[8][4];
  #pragma unroll
  for (int mb = 0; mb < 8; ++mb) {
    f32x4 c0v = *(const f32x4*)(cc + b * 512 + (8 * w + mb) * 16 + g * 4);
    #pragma unroll
    for (int nb = 0; nb < 4; ++nb) acc[mb][nb] = c0v;
  }
  for (int ks = 0; ks < 4; ++ks) {
    #pragma unroll
    for (int i = 0; i < 8; ++i) {
      int u = t + i * 256;
      int c = u >> 2, s8 = u & 3;
      *(short8_t*)&ldsW[c * 40 + s8 * 8] = *(const short8_t*)(w1eT + (size_t)c * 128 + ks * 32 + s8 * 8);
    }
    __syncthreads();
    short8_t bb[4];
    #pragma unroll
    for (int nb = 0; nb < 4; ++nb) bb[nb] = *(short8_t*)&ldsE[(nb * 16 + ln) * 136 + ks * 32 + g * 8];
    #pragma unroll
    for (int mb = 0; mb < 8; ++mb) {
      short8_t a = *(short8_t*)&ldsW[((8 * w + mb) * 16 + ln) * 40 + g * 8];
      #pragma unroll
      for (int nb = 0; nb < 4; ++nb)
        acc[mb][nb] = __builtin_amdgcn_mfma_f32_16x16x32_bf16(a, bb[nb], acc[mb][nb], 0, 0, 0);
    }
    __syncthreads();
  }
  #pragma unroll
  for (int mb = 0; mb < 8; ++mb) {
    int c0 = (8 * w + mb) * 16 + g * 4;
    #pragma unroll
    for (int nb = 0; nb < 4; ++nb) {
      int r = nb * 16 + ln;
      f32x4 v = acc[mb][nb];
      short4_t p;
      p[0] = (short)f2bf(fmaxf(v[0], 0.f)); p[1] = (short)f2bf(fmaxf(v[1], 0.f));
      p[2] = (short)f2bf(fmaxf(v[2], 0.f)); p[3] = (short)f2bf(fmaxf(v[3], 0.f));
      *(short4_t*)&ldsA[r * 520 + c0] = p;
    }
  }
  __syncthreads();

  // ===== Stage 2: H2T[c][r] = b2[c] + sum_k w2T[c][k]*H1T[k][r]
  #pragma unroll
  for (int mb = 0; mb < 8; ++mb) {
    f32x4 b2v = *(const f32x4*)(b2 + (8 * w + mb) * 16 + g * 4);
    #pragma unroll
    for (int nb = 0; nb < 4; ++nb) acc[mb][nb] = b2v;
  }
  for (int ks = 0; ks < 16; ++ks) {
    #pragma unroll
    for (int i = 0; i < 8; ++i) {
      int u = t + i * 256;
      int c = u >> 2, s8 = u & 3;
      *(short8_t*)&ldsW[c * 40 + s8 * 8] = *(const short8_t*)(w2T + (size_t)c * 512 + ks * 32 + s8 * 8);
    }
    __syncthreads();
    short8_t bb[4];
    #pragma unroll
    for (int nb = 0; nb < 4; ++nb) bb[nb] = *(short8_t*)&ldsA[(nb * 16 + ln) * 520 + ks * 32 + g * 8];
    #pragma unroll
    for (int mb = 0; mb < 8; ++mb) {
      short8_t a = *(short8_t*)&ldsW[((8 * w + mb) * 16 + ln) * 40 + g * 8];
      #pragma unroll
      for (int nb = 0; nb < 4; ++nb)
        acc[mb][nb] = __builtin_amdgcn_mfma_f32_16x16x32_bf16(a, bb[nb], acc[mb][nb], 0, 0, 0);
    }
    __syncthreads();
  }

  // ===== Stage 3: q[r] = relu(b3 + sum_c relu(H2T[c][r]) * w3[c])
  float part[4] = {0.f, 0.f, 0.f, 0.f};
  #pragma unroll
  for (int mb = 0; mb < 8; ++mb) {
    int c0 = (8 * w + mb) * 16 + g * 4;
    f32x4 w3v = *(const f32x4*)(W3 + c0);
    #pragma unroll
    for (int nb = 0; nb < 4; ++nb) {
      f32x4 v = acc[mb][nb];
      part[nb] += fmaxf(v[0], 0.f) * w3v[0] + fmaxf(v[1], 0.f) * w3v[1]
                + fmaxf(v[2], 0.f) * w3v[2] + fmaxf(v[3], 0.f) * w3v[3];
    }
  }
  #pragma unroll
  for (int nb = 0; nb < 4; ++nb) {
    float p = part[nb];
    p += __shfl_xor(p, 16, 64);
    p += __shfl_xor(p, 32, 64);
    if (g == 0) qpart[w][nb * 16 + ln] = p;
  }
  __syncthreads();
  if (t < 64) {
    float q = qpart[0][t] + qpart[1][t] + qpart[2][t] + qpart[3][t] + b3[0];
    qout[(size_t)b * 512 + l0 + t] = fmaxf(q, 0.f);
  }
}

extern "C" void kernel_launch(void* const* d_in, const int* in_sizes, int n_in,
                              void* d_out, int out_size, void* d_ws, size_t ws_size,
                              hipStream_t stream) {
  (void)in_sizes; (void)n_in; (void)out_size; (void)ws_size;
  const float* instr  = (const float*)d_in[0];
  const float* state  = (const float*)d_in[1];
  const float* hidden = (const float*)d_in[2];
  const float* adesc  = (const float*)d_in[3];
  const float* astd   = (const float*)d_in[4];
  const int*   tids   = (const int*)d_in[5];
  const int*   lens   = (const int*)d_in[6];
  const float* Wd = (const float*)d_in[7];
  const float* bd = (const float*)d_in[8];
  const float* Ws = (const float*)d_in[9];
  const float* bs = (const float*)d_in[10];
  const float* W1 = (const float*)d_in[11];
  const float* b1 = (const float*)d_in[12];
  const float* W2 = (const float*)d_in[13];
  const float* b2 = (const float*)d_in[14];
  const float* W3 = (const float*)d_in[15];
  const float* b3 = (const float*)d_in[16];

  float* qout = (float*)d_out;
  float* embout = qout + 128 * 512;

  char* ws = (char*)d_ws;
  unsigned short* wdT  = (unsigned short*)(ws);            // 128x768 bf16 = 196608 B
  unsigned short* wsT  = (unsigned short*)(ws + 196608);   // 128x128 bf16 =  32768 B
  unsigned short* w1eT = (unsigned short*)(ws + 229376);   // 512x128 bf16 = 131072 B
  unsigned short* w2T  = (unsigned short*)(ws + 360448);   // 512x512 bf16 = 524288 B
  float* cc   = (float*)(ws + 884736);                     // 128x512 f32  = 262144 B
  float* qinv = (float*)(ws + 1146880);                    // 128 f32

  prep_weights<<<256, 256, 0, stream>>>(Wd, Ws, W1, W2, wdT, wsT, w1eT, w2T);
  ctx_cc<<<512, 256, 0, stream>>>(instr, state, hidden, W1, b1, cc);
  qinv_kernel<<<128, 256, 0, stream>>>(cc, W2, b2, W3, b3, qinv);
  dim3 grid(8, 128);
  flatcritic_main<<<grid, 256, 0, stream>>>(adesc, astd, tids, lens, bd, bs, b2, W3, b3,
                                            wdT, wsT, w1eT, w2T, cc, qinv, qout, embout);
}

// Round 2
// 190.649 us; speedup vs baseline: 1.2903x; 1.2903x over previous
//
#include <hip/hip_runtime.h>
#include <stdint.h>

// FlatCritic: B=128, L=512, D_DESC=768, D_STD=128, D_ACT=128, D_CTX=1152, H=512
// out = [q (B*L f32), emb (B*L*128 f32)]
//
// v2: fragment-packed weights (global->reg A-frags, no LDS staging, no barriers
// in S1/S2 loops), 512-thread blocks, LDS arena reuse (act | ldsE | H1),
// cc via small MFMA GEMM, qinv on bf16 W2.

typedef __attribute__((ext_vector_type(8))) short short8_t;
typedef __attribute__((ext_vector_type(4))) short short4_t;
typedef __attribute__((ext_vector_type(4))) float f32x4;

__device__ inline unsigned short f2bf(float f) {
  union { float f; unsigned u; } v; v.f = f;
  unsigned r = v.u + 0x7FFFu + ((v.u >> 16) & 1u);
  return (unsigned short)(r >> 16);
}

// pack W (f32, [K][C] row-major: val(c,k)=src[k*ldc+c]) into MFMA A-frag layout:
// dst[((mb*NKS+ks)*64+lane)*8+j] = bf16( src[(k0+ks*32+(lane>>4)*8+j)*ldc + mb*16+(lane&15)] )
__device__ inline void pack_frags(const float* __restrict__ src, int ldc, int k0, int NKS,
                                  unsigned short* __restrict__ dst, int total, int tid, int n) {
  for (int fi = tid; fi < total; fi += n) {
    int j = fi & 7, lane = (fi >> 3) & 63, rest = fi >> 9;
    int ks = rest % NKS, mb = rest / NKS;
    int c = mb * 16 + (lane & 15);
    int k = k0 + ks * 32 + ((lane >> 4) << 3) + j;
    dst[fi] = f2bf(src[(size_t)k * ldc + c]);
  }
}

__global__ __launch_bounds__(256) void prep_pack(
    const float* __restrict__ Wd, const float* __restrict__ Ws,
    const float* __restrict__ W1, const float* __restrict__ W2,
    const float* __restrict__ instr, const float* __restrict__ state,
    const float* __restrict__ hidden,
    unsigned short* __restrict__ wdf, unsigned short* __restrict__ wsf,
    unsigned short* __restrict__ w1f, unsigned short* __restrict__ w2f,
    unsigned short* __restrict__ w1cf, unsigned short* __restrict__ w2p,
    unsigned short* __restrict__ ctxb) {
  int tid = blockIdx.x * 256 + threadIdx.x, n = gridDim.x * 256;
  pack_frags(Wd, 128, 0,    24, wdf,  98304,  tid, n);   // desc proj  [8mb][24ks]
  pack_frags(Ws, 128, 0,    4,  wsf,  16384,  tid, n);   // std proj   [8mb][4ks]
  pack_frags(W1, 512, 1152, 4,  w1f,  65536,  tid, n);   // W1[1152:]  [32mb][4ks]
  pack_frags(W2, 512, 0,    16, w2f,  262144, tid, n);   // W2         [32mb][16ks]
  pack_frags(W1, 512, 0,    36, w1cf, 589824, tid, n);   // W1[:1152]  [32mb][36ks]
  for (int i = tid; i < 262144; i += n) w2p[i] = f2bf(W2[i]);  // plain bf16 W2 (qinv)
  for (int i = tid; i < 147456; i += n) {                      // ctx concat bf16 [128][1152]
    int bb = i / 1152, k = i % 1152;
    float v = (k < 512) ? instr[bb * 512 + k]
            : (k < 1024) ? state[bb * 512 + k - 512]
                         : hidden[bb * 128 + k - 1024];
    ctxb[i] = f2bf(v);
  }
}

// cc[b][c] = b1[c] + ctx(b).W1[:1152,c]   via MFMA, grid (16 c-parts, 4 b-parts)
__global__ __launch_bounds__(256) void cc_mfma(
    const unsigned short* __restrict__ ctxb, const unsigned short* __restrict__ w1cf,
    const float* __restrict__ b1, float* __restrict__ ccout) {
  int bx = blockIdx.x, by = blockIdx.y;
  int t = threadIdx.x, w = t >> 6, l = t & 63, g = l >> 4, ln = l & 15;
  int wc = w & 1, wr = w >> 1;
  __shared__ __align__(16) unsigned short ldsC[32 * 136];
  f32x4 acc = {0.f, 0.f, 0.f, 0.f};
  for (int kc = 0; kc < 9; ++kc) {
    __syncthreads();
    #pragma unroll
    for (int i = 0; i < 2; ++i) {
      int u = t + i * 256;
      int bl = u >> 4, k8 = u & 15;
      *(short8_t*)&ldsC[bl * 136 + k8 * 8] =
          *(const short8_t*)(ctxb + (size_t)(by * 32 + bl) * 1152 + kc * 128 + k8 * 8);
    }
    __syncthreads();
    #pragma unroll
    for (int ks = 0; ks < 4; ++ks) {
      short8_t a = *(const short8_t*)(w1cf + ((((size_t)(bx * 2 + wc) * 36 + kc * 4 + ks) * 64 + l) << 3));
      short8_t bb = *(const short8_t*)&ldsC[(wr * 16 + ln) * 136 + ks * 32 + g * 8];
      acc = __builtin_amdgcn_mfma_f32_16x16x32_bf16(a, bb, acc, 0, 0, 0);
    }
  }
  int c = bx * 32 + wc * 16 + g * 4;
  int bb_ = by * 32 + wr * 16 + ln;
  f32x4 b1v = *(const f32x4*)(b1 + c);
  *(f32x4*)(ccout + (size_t)bb_ * 512 + c) = acc + b1v;
}

// q_inv[b] = MLP tail on h1 = relu(cc[b])  (bf16 W2 reads)
__global__ __launch_bounds__(256) void qinv_kernel(
    const float* __restrict__ cc, const unsigned short* __restrict__ w2p,
    const float* __restrict__ b2, const float* __restrict__ W3,
    const float* __restrict__ b3, float* __restrict__ qinv) {
  int b = blockIdx.x, t = threadIdx.x;
  __shared__ float h1s[512];
  __shared__ float red[256];
  for (int i = t; i < 512; i += 256) h1s[i] = fmaxf(cc[b * 512 + i], 0.f);
  __syncthreads();
  int c2 = t * 2;
  float a0 = b2[c2], a1 = b2[c2 + 1];
  #pragma unroll 4
  for (int c = 0; c < 512; ++c) {
    float x = h1s[c];
    unsigned u = *(const unsigned*)&w2p[c * 512 + c2];
    union { unsigned u; float f; } lo, hi;
    lo.u = (u & 0xFFFFu) << 16; hi.u = u & 0xFFFF0000u;
    a0 = fmaf(x, lo.f, a0); a1 = fmaf(x, hi.f, a1);
  }
  red[t] = fmaxf(a0, 0.f) * W3[c2] + fmaxf(a1, 0.f) * W3[c2 + 1];
  __syncthreads();
  for (int s = 128; s > 0; s >>= 1) { if (t < s) red[t] += red[t + s]; __syncthreads(); }
  if (t == 0) qinv[b] = fmaxf(red[0] + b3[0], 0.f);
}

// ---------------- main: 512 threads, 64-row tile, grid (8, 128) ----------------
__global__ __launch_bounds__(512, 2) void flatcritic_main(
    const float* __restrict__ adesc, const float* __restrict__ astd,
    const int* __restrict__ type_ids, const int* __restrict__ lengths,
    const float* __restrict__ bdesc, const float* __restrict__ bstd,
    const float* __restrict__ b2, const float* __restrict__ W3, const float* __restrict__ b3,
    const unsigned short* __restrict__ wdf, const unsigned short* __restrict__ wsf,
    const unsigned short* __restrict__ w1f, const unsigned short* __restrict__ w2f,
    const float* __restrict__ cc, const float* __restrict__ qinv,
    float* __restrict__ qout, float* __restrict__ embout) {
  int b = blockIdx.y, lt = blockIdx.x;
  int l0 = lt * 64;
  int t = threadIdx.x;
  int len = lengths[b];
  int nv = len - l0; nv = nv < 0 ? 0 : (nv > 64 ? 64 : nv);
  f32x4 zero4 = {0.f, 0.f, 0.f, 0.f};

  if (nv == 0) {  // fully-invalid tile: q = q_inv, emb = 0
    float qv = qinv[b];
    if (t < 64) qout[(size_t)b * 512 + l0 + t] = qv;
    float* ep = embout + (size_t)(b * 512 + l0) * 128;
    #pragma unroll
    for (int i = 0; i < 4; ++i) ((f32x4*)ep)[t + i * 512] = zero4;
    return;
  }

  // LDS arena: [0:8704) actbuf0 | [8704:17408) actbuf1 | [17408:26112) ldsE
  // after S1: whole arena = H1 [64][520]
  __shared__ __align__(16) unsigned short arena[64 * 520];
  __shared__ int typeL[64];
  __shared__ float qpart[8][64];

  int w = t >> 6, l = t & 63, g = l >> 4, ln = l & 15;

  if (t < 64) typeL[t] = type_ids[b * 512 + l0 + t];
  __syncthreads();

  const float* descB = adesc + (size_t)(b * 512 + l0) * 768;
  const float* stdB  = astd  + (size_t)(b * 512 + l0) * 128;

  // ===== Stage P: embT[k][r], K = 6*128 desc + 128 std, double-buffered action staging
  f32x4 embacc[4];
  #pragma unroll
  for (int nb = 0; nb < 4; ++nb) embacc[nb] = zero4;

  // stage chunk kc into buf kc&1
  auto stageact = [&](int kc) {
    unsigned short* buf = arena + (kc & 1) * 8704;
    bool isStd = (kc == 6);
    #pragma unroll
    for (int i = 0; i < 4; ++i) {
      int u = t + i * 512;
      int r = u >> 5, c4 = u & 31;
      bool ok = (r < nv) && ((typeL[r] == 0) != isStd);
      f32x4 v = zero4;
      if (ok) v = isStd ? *(const f32x4*)(stdB + (size_t)r * 128 + c4 * 4)
                        : *(const f32x4*)(descB + (size_t)r * 768 + kc * 128 + c4 * 4);
      short4_t p; p[0] = (short)f2bf(v[0]); p[1] = (short)f2bf(v[1]);
      p[2] = (short)f2bf(v[2]); p[3] = (short)f2bf(v[3]);
      *(short4_t*)&buf[r * 136 + c4 * 4] = p;
    }
  };

  stageact(0);
  for (int kc = 0; kc < 7; ++kc) {
    __syncthreads();               // prev MFMA reads of buf (kc+1)&1 are done
    if (kc < 6) stageact(kc + 1);  // write other buffer
    const unsigned short* buf = arena + (kc & 1) * 8704;
    bool isStd = (kc == 6);
    #pragma unroll
    for (int ks = 0; ks < 4; ++ks) {
      const unsigned short* ap = isStd ? (wsf + (((w * 4 + ks) * 64 + l) << 3))
                                       : (wdf + (((w * 24 + kc * 4 + ks) * 64 + l) << 3));
      short8_t a = *(const short8_t*)ap;
      #pragma unroll
      for (int nb = 0; nb < 4; ++nb) {
        short8_t bb = *(const short8_t*)&buf[(nb * 16 + ln) * 136 + ks * 32 + g * 8];
        embacc[nb] = __builtin_amdgcn_mfma_f32_16x16x32_bf16(a, bb, embacc[nb], 0, 0, 0);
      }
    }
  }
  __syncthreads();  // all P MFMAs done before ldsE region written

  // bias (masked) + write emb f32 global + bf16 -> ldsE (arena+17408)
  {
    unsigned short* ldsE = arena + 17408;
    int k0 = w * 16 + g * 4;
    f32x4 bd4 = *(const f32x4*)(bdesc + k0);
    f32x4 bs4 = *(const f32x4*)(bstd + k0);
    #pragma unroll
    for (int nb = 0; nb < 4; ++nb) {
      int r = nb * 16 + ln;
      f32x4 e = embacc[nb];
      if (r < nv) { f32x4 bias = (typeL[r] == 0) ? bd4 : bs4; e = e + bias; }
      else e = zero4;
      *(f32x4*)(embout + (size_t)(b * 512 + l0 + r) * 128 + k0) = e;
      short4_t p; p[0] = (short)f2bf(e[0]); p[1] = (short)f2bf(e[1]);
      p[2] = (short)f2bf(e[2]); p[3] = (short)f2bf(e[3]);
      *(short4_t*)&ldsE[r * 136 + k0] = p;
    }
  }
  __syncthreads();

  // ===== Stage 1: H1T[c][r] = cc[b][c] + sum_k W1e[k][c]*emb[r][k]  (A from global frags)
  f32x4 acc1[4][4];
  #pragma unroll
  for (int mbi = 0; mbi < 4; ++mbi) {
    f32x4 ccv = *(const f32x4*)(cc + (size_t)b * 512 + w * 64 + mbi * 16 + g * 4);
    #pragma unroll
    for (int nb = 0; nb < 4; ++nb) acc1[mbi][nb] = ccv;
  }
  {
    const unsigned short* ldsE = arena + 17408;
    #pragma unroll
    for (int ks = 0; ks < 4; ++ks) {
      short8_t bfr[4];
      #pragma unroll
      for (int nb = 0; nb < 4; ++nb)
        bfr[nb] = *(const short8_t*)&ldsE[(nb * 16 + ln) * 136 + ks * 32 + g * 8];
      #pragma unroll
      for (int mbi = 0; mbi < 4; ++mbi) {
        short8_t a = *(const short8_t*)(w1f + ((((w * 4 + mbi) * 4 + ks) * 64 + l) << 3));
        #pragma unroll
        for (int nb = 0; nb < 4; ++nb)
          acc1[mbi][nb] = __builtin_amdgcn_mfma_f32_16x16x32_bf16(a, bfr[nb], acc1[mbi][nb], 0, 0, 0);
      }
    }
  }
  __syncthreads();  // everyone done reading ldsE; arena free for H1

  // relu + pack H1 bf16 -> arena [64][520]
  #pragma unroll
  for (int mbi = 0; mbi < 4; ++mbi) {
    int c0 = w * 64 + mbi * 16 + g * 4;
    #pragma unroll
    for (int nb = 0; nb < 4; ++nb) {
      int r = nb * 16 + ln;
      f32x4 v = acc1[mbi][nb];
      short4_t p;
      p[0] = (short)f2bf(fmaxf(v[0], 0.f)); p[1] = (short)f2bf(fmaxf(v[1], 0.f));
      p[2] = (short)f2bf(fmaxf(v[2], 0.f)); p[3] = (short)f2bf(fmaxf(v[3], 0.f));
      *(short4_t*)&arena[r * 520 + c0] = p;
    }
  }
  __syncthreads();

  // ===== Stage 2: H2T[c2][r] = b2[c2] + sum_c1 W2[c1][c2]*H1[r][c1]  (A from global frags)
  f32x4 acc2[4][4];
  #pragma unroll
  for (int mbi = 0; mbi < 4; ++mbi) {
    f32x4 b2v = *(const f32x4*)(b2 + w * 64 + mbi * 16 + g * 4);
    #pragma unroll
    for (int nb = 0; nb < 4; ++nb) acc2[mbi][nb] = b2v;
  }
  #pragma unroll
  for (int ks = 0; ks < 16; ++ks) {
    short8_t bfr[4];
    #pragma unroll
    for (int nb = 0; nb < 4; ++nb)
      bfr[nb] = *(const short8_t*)&arena[(nb * 16 + ln) * 520 + ks * 32 + g * 8];
    #pragma unroll
    for (int mbi = 0; mbi < 4; ++mbi) {
      short8_t a = *(const short8_t*)(w2f + ((((w * 4 + mbi) * 16 + ks) * 64 + l) << 3));
      #pragma unroll
      for (int nb = 0; nb < 4; ++nb)
        acc2[mbi][nb] = __builtin_amdgcn_mfma_f32_16x16x32_bf16(a, bfr[nb], acc2[mbi][nb], 0, 0, 0);
    }
  }

  // ===== Stage 3: q[r] = relu(b3 + sum_c2 relu(H2)*W3)
  float part[4] = {0.f, 0.f, 0.f, 0.f};
  #pragma unroll
  for (int mbi = 0; mbi < 4; ++mbi) {
    int c0 = w * 64 + mbi * 16 + g * 4;
    f32x4 w3v = *(const f32x4*)(W3 + c0);
    #pragma unroll
    for (int nb = 0; nb < 4; ++nb) {
      f32x4 v = acc2[mbi][nb];
      part[nb] += fmaxf(v[0], 0.f) * w3v[0] + fmaxf(v[1], 0.f) * w3v[1]
                + fmaxf(v[2], 0.f) * w3v[2] + fmaxf(v[3], 0.f) * w3v[3];
    }
  }
  #pragma unroll
  for (int nb = 0; nb < 4; ++nb) {
    float p = part[nb];
    p += __shfl_xor(p, 16, 64);
    p += __shfl_xor(p, 32, 64);
    if (g == 0) qpart[w][nb * 16 + ln] = p;
  }
  __syncthreads();
  if (t < 64) {
    float q = qpart[0][t] + qpart[1][t] + qpart[2][t] + qpart[3][t]
            + qpart[4][t] + qpart[5][t] + qpart[6][t] + qpart[7][t] + b3[0];
    qout[(size_t)b * 512 + l0 + t] = fmaxf(q, 0.f);
  }
}

extern "C" void kernel_launch(void* const* d_in, const int* in_sizes, int n_in,
                              void* d_out, int out_size, void* d_ws, size_t ws_size,
                              hipStream_t stream) {
  (void)in_sizes; (void)n_in; (void)out_size; (void)ws_size;
  const float* instr  = (const float*)d_in[0];
  const float* state  = (const float*)d_in[1];
  const float* hidden = (const float*)d_in[2];
  const float* adesc  = (const float*)d_in[3];
  const float* astd   = (const float*)d_in[4];
  const int*   tids   = (const int*)d_in[5];
  const int*   lens   = (const int*)d_in[6];
  const float* Wd = (const float*)d_in[7];
  const float* bd = (const float*)d_in[8];
  const float* Ws = (const float*)d_in[9];
  const float* bs = (const float*)d_in[10];
  const float* W1 = (const float*)d_in[11];
  const float* b1 = (const float*)d_in[12];
  const float* W2 = (const float*)d_in[13];
  const float* b2 = (const float*)d_in[14];
  const float* W3 = (const float*)d_in[15];
  const float* b3 = (const float*)d_in[16];

  float* qout = (float*)d_out;
  float* embout = qout + 128 * 512;

  char* ws = (char*)d_ws;
  unsigned short* wdf  = (unsigned short*)(ws);             // 196608 B
  unsigned short* wsf  = (unsigned short*)(ws + 196608);    //  32768 B
  unsigned short* w1f  = (unsigned short*)(ws + 229376);    // 131072 B
  unsigned short* w2f  = (unsigned short*)(ws + 360448);    // 524288 B
  unsigned short* w1cf = (unsigned short*)(ws + 884736);    // 1179648 B
  unsigned short* w2p  = (unsigned short*)(ws + 2064384);   // 524288 B
  unsigned short* ctxb = (unsigned short*)(ws + 2588672);   // 294912 B
  float* cc   = (float*)(ws + 2883584);                     // 262144 B
  float* qinv = (float*)(ws + 3145728);                     // 512 B

  prep_pack<<<512, 256, 0, stream>>>(Wd, Ws, W1, W2, instr, state, hidden,
                                     wdf, wsf, w1f, w2f, w1cf, w2p, ctxb);
  cc_mfma<<<dim3(16, 4), 256, 0, stream>>>(ctxb, w1cf, b1, cc);
  qinv_kernel<<<128, 256, 0, stream>>>(cc, w2p, b2, W3, b3, qinv);
  dim3 grid(8, 128);
  flatcritic_main<<<grid, 512, 0, stream>>>(adesc, astd, tids, lens, bd, bs, b2, W3, b3,
                                            wdf, wsf, w1f, w2f, cc, qinv, qout, embout);
}

// Round 3
// 177.346 us; speedup vs baseline: 1.3871x; 1.0750x over previous
//
#include <hip/hip_runtime.h>
#include <stdint.h>

// FlatCritic: B=128, L=512, D_DESC=768, D_STD=128, D_ACT=128, D_CTX=1152, H=512
// out = [q (B*L f32), emb (B*L*128 f32)]
//
// v3: split emb-producer (E: 32-row tiles, tiny LDS, 8 blocks/CU, T14 reg-split
// staging) from MLP consumer (M: 64-row tiles, S1 B-frags direct from global
// embout, ~3 barriers). prep/cc/qinv unchanged from v2.

typedef __attribute__((ext_vector_type(8))) short short8_t;
typedef __attribute__((ext_vector_type(4))) short short4_t;
typedef __attribute__((ext_vector_type(4))) float f32x4;

__device__ inline unsigned short f2bf(float f) {
  union { float f; unsigned u; } v; v.f = f;
  unsigned r = v.u + 0x7FFFu + ((v.u >> 16) & 1u);
  return (unsigned short)(r >> 16);
}

// pack W (f32, [K][C] row-major: val(c,k)=src[k*ldc+c]) into MFMA A-frag layout:
// dst[((mb*NKS+ks)*64+lane)*8+j] = bf16( src[(k0+ks*32+(lane>>4)*8+j)*ldc + mb*16+(lane&15)] )
__device__ inline void pack_frags(const float* __restrict__ src, int ldc, int k0, int NKS,
                                  unsigned short* __restrict__ dst, int total, int tid, int n) {
  for (int fi = tid; fi < total; fi += n) {
    int j = fi & 7, lane = (fi >> 3) & 63, rest = fi >> 9;
    int ks = rest % NKS, mb = rest / NKS;
    int c = mb * 16 + (lane & 15);
    int k = k0 + ks * 32 + ((lane >> 4) << 3) + j;
    dst[fi] = f2bf(src[(size_t)k * ldc + c]);
  }
}

__global__ __launch_bounds__(256) void prep_pack(
    const float* __restrict__ Wd, const float* __restrict__ Ws,
    const float* __restrict__ W1, const float* __restrict__ W2,
    const float* __restrict__ instr, const float* __restrict__ state,
    const float* __restrict__ hidden,
    unsigned short* __restrict__ wdf, unsigned short* __restrict__ wsf,
    unsigned short* __restrict__ w1f, unsigned short* __restrict__ w2f,
    unsigned short* __restrict__ w1cf, unsigned short* __restrict__ w2p,
    unsigned short* __restrict__ ctxb) {
  int tid = blockIdx.x * 256 + threadIdx.x, n = gridDim.x * 256;
  pack_frags(Wd, 128, 0,    24, wdf,  98304,  tid, n);   // desc proj  [8mb][24ks]
  pack_frags(Ws, 128, 0,    4,  wsf,  16384,  tid, n);   // std proj   [8mb][4ks]
  pack_frags(W1, 512, 1152, 4,  w1f,  65536,  tid, n);   // W1[1152:]  [32mb][4ks]
  pack_frags(W2, 512, 0,    16, w2f,  262144, tid, n);   // W2         [32mb][16ks]
  pack_frags(W1, 512, 0,    36, w1cf, 589824, tid, n);   // W1[:1152]  [32mb][36ks]
  for (int i = tid; i < 262144; i += n) w2p[i] = f2bf(W2[i]);  // plain bf16 W2 (qinv)
  for (int i = tid; i < 147456; i += n) {                      // ctx concat bf16 [128][1152]
    int bb = i / 1152, k = i % 1152;
    float v = (k < 512) ? instr[bb * 512 + k]
            : (k < 1024) ? state[bb * 512 + k - 512]
                         : hidden[bb * 128 + k - 1024];
    ctxb[i] = f2bf(v);
  }
}

// cc[b][c] = b1[c] + ctx(b).W1[:1152,c]   via MFMA, grid (16 c-parts, 4 b-parts)
__global__ __launch_bounds__(256) void cc_mfma(
    const unsigned short* __restrict__ ctxb, const unsigned short* __restrict__ w1cf,
    const float* __restrict__ b1, float* __restrict__ ccout) {
  int bx = blockIdx.x, by = blockIdx.y;
  int t = threadIdx.x, w = t >> 6, l = t & 63, g = l >> 4, ln = l & 15;
  int wc = w & 1, wr = w >> 1;
  __shared__ __align__(16) unsigned short ldsC[32 * 136];
  f32x4 acc = {0.f, 0.f, 0.f, 0.f};
  for (int kc = 0; kc < 9; ++kc) {
    __syncthreads();
    #pragma unroll
    for (int i = 0; i < 2; ++i) {
      int u = t + i * 256;
      int bl = u >> 4, k8 = u & 15;
      *(short8_t*)&ldsC[bl * 136 + k8 * 8] =
          *(const short8_t*)(ctxb + (size_t)(by * 32 + bl) * 1152 + kc * 128 + k8 * 8);
    }
    __syncthreads();
    #pragma unroll
    for (int ks = 0; ks < 4; ++ks) {
      short8_t a = *(const short8_t*)(w1cf + ((((size_t)(bx * 2 + wc) * 36 + kc * 4 + ks) * 64 + l) << 3));
      short8_t bb = *(const short8_t*)&ldsC[(wr * 16 + ln) * 136 + ks * 32 + g * 8];
      acc = __builtin_amdgcn_mfma_f32_16x16x32_bf16(a, bb, acc, 0, 0, 0);
    }
  }
  int c = bx * 32 + wc * 16 + g * 4;
  int bb_ = by * 32 + wr * 16 + ln;
  f32x4 b1v = *(const f32x4*)(b1 + c);
  *(f32x4*)(ccout + (size_t)bb_ * 512 + c) = acc + b1v;
}

// q_inv[b] = MLP tail on h1 = relu(cc[b])  (bf16 W2 reads)
__global__ __launch_bounds__(256) void qinv_kernel(
    const float* __restrict__ cc, const unsigned short* __restrict__ w2p,
    const float* __restrict__ b2, const float* __restrict__ W3,
    const float* __restrict__ b3, float* __restrict__ qinv) {
  int b = blockIdx.x, t = threadIdx.x;
  __shared__ float h1s[512];
  __shared__ float red[256];
  for (int i = t; i < 512; i += 256) h1s[i] = fmaxf(cc[b * 512 + i], 0.f);
  __syncthreads();
  int c2 = t * 2;
  float a0 = b2[c2], a1 = b2[c2 + 1];
  #pragma unroll 4
  for (int c = 0; c < 512; ++c) {
    float x = h1s[c];
    unsigned u = *(const unsigned*)&w2p[c * 512 + c2];
    union { unsigned u; float f; } lo, hi;
    lo.u = (u & 0xFFFFu) << 16; hi.u = u & 0xFFFF0000u;
    a0 = fmaf(x, lo.f, a0); a1 = fmaf(x, hi.f, a1);
  }
  red[t] = fmaxf(a0, 0.f) * W3[c2] + fmaxf(a1, 0.f) * W3[c2 + 1];
  __syncthreads();
  for (int s = 128; s > 0; s >>= 1) { if (t < s) red[t] += red[t + s]; __syncthreads(); }
  if (t == 0) qinv[b] = fmaxf(red[0] + b3[0], 0.f);
}

// ---------------- E: emb producer. 32-row tiles, 256 threads, grid (16,128) ----------------
__global__ __launch_bounds__(256) void emb_kernel(
    const float* __restrict__ adesc, const float* __restrict__ astd,
    const int* __restrict__ type_ids, const int* __restrict__ lengths,
    const float* __restrict__ bdesc, const float* __restrict__ bstd,
    const unsigned short* __restrict__ wdf, const unsigned short* __restrict__ wsf,
    float* __restrict__ embout) {
  int b = blockIdx.y, lt = blockIdx.x;
  int l0 = lt * 32;
  int t = threadIdx.x;
  int len = lengths[b];
  int nv = len - l0; nv = nv < 0 ? 0 : (nv > 32 ? 32 : nv);
  f32x4 zero4 = {0.f, 0.f, 0.f, 0.f};

  if (nv == 0) {  // fully-invalid tile: emb = 0 (q handled by M)
    float* ep = embout + (size_t)(b * 512 + l0) * 128;
    #pragma unroll
    for (int i = 0; i < 4; ++i) ((f32x4*)ep)[t + i * 256] = zero4;
    return;
  }

  __shared__ __align__(16) unsigned short act[2][32 * 136];
  __shared__ int typeL[32];
  int w = t >> 6, l = t & 63, g = l >> 4, ln = l & 15;

  if (t < 32) typeL[t] = type_ids[b * 512 + l0 + t];

  const float* descB = adesc + (size_t)(b * 512 + l0) * 768;
  const float* stdB  = astd  + (size_t)(b * 512 + l0) * 128;

  __syncthreads();  // typeL ready

  // reg-split staging (T14): issue -> [MFMA prev] -> write
  f32x4 stg[4];
  int r0 = t >> 5, c4 = t & 31;  // each thread stages rows r0, r0+8, r0+16, r0+24 at col quad c4

  auto issue = [&](int kc) {
    bool isStd = (kc == 6);
    #pragma unroll
    for (int i = 0; i < 4; ++i) {
      int r = r0 + i * 8;
      bool ok = (r < nv) && ((typeL[r] == 0) != isStd);
      f32x4 v = zero4;
      if (ok) v = isStd ? *(const f32x4*)(stdB + (size_t)r * 128 + c4 * 4)
                        : *(const f32x4*)(descB + (size_t)r * 768 + kc * 128 + c4 * 4);
      stg[i] = v;
    }
  };
  auto writebuf = [&](int kc) {
    unsigned short* buf = act[kc & 1];
    #pragma unroll
    for (int i = 0; i < 4; ++i) {
      short4_t p;
      p[0] = (short)f2bf(stg[i][0]); p[1] = (short)f2bf(stg[i][1]);
      p[2] = (short)f2bf(stg[i][2]); p[3] = (short)f2bf(stg[i][3]);
      *(short4_t*)&buf[(r0 + i * 8) * 136 + c4 * 4] = p;
    }
  };

  issue(0); writebuf(0);

  f32x4 acc[2][2];
  #pragma unroll
  for (int mb = 0; mb < 2; ++mb)
    #pragma unroll
    for (int nb = 0; nb < 2; ++nb) acc[mb][nb] = zero4;

  for (int kc = 0; kc < 7; ++kc) {
    __syncthreads();  // buf[kc&1] writes visible; all prev reads of buf[(kc+1)&1] done
    if (kc < 6) issue(kc + 1);
    const unsigned short* buf = act[kc & 1];
    bool isStd = (kc == 6);
    #pragma unroll
    for (int ks = 0; ks < 4; ++ks) {
      short8_t bfr[2];
      #pragma unroll
      for (int nb = 0; nb < 2; ++nb)
        bfr[nb] = *(const short8_t*)&buf[(nb * 16 + ln) * 136 + ks * 32 + g * 8];
      #pragma unroll
      for (int mb = 0; mb < 2; ++mb) {
        const unsigned short* ap = isStd ? (wsf + ((((w * 2 + mb) * 4 + ks) * 64 + l) << 3))
                                         : (wdf + ((((w * 2 + mb) * 24 + kc * 4 + ks) * 64 + l) << 3));
        short8_t a = *(const short8_t*)ap;
        #pragma unroll
        for (int nb = 0; nb < 2; ++nb)
          acc[mb][nb] = __builtin_amdgcn_mfma_f32_16x16x32_bf16(a, bfr[nb], acc[mb][nb], 0, 0, 0);
      }
    }
    if (kc < 6) writebuf(kc + 1);
  }

  // epilogue: masked bias + direct global store (no LDS, no barrier)
  #pragma unroll
  for (int mb = 0; mb < 2; ++mb) {
    int k0 = w * 32 + mb * 16 + g * 4;
    f32x4 bd4 = *(const f32x4*)(bdesc + k0);
    f32x4 bs4 = *(const f32x4*)(bstd + k0);
    #pragma unroll
    for (int nb = 0; nb < 2; ++nb) {
      int r = nb * 16 + ln;
      f32x4 e = acc[mb][nb];
      if (r < nv) { f32x4 bias = (typeL[r] == 0) ? bd4 : bs4; e = e + bias; }
      else e = zero4;
      *(f32x4*)(embout + (size_t)(b * 512 + l0 + r) * 128 + k0) = e;
    }
  }
}

// ---------------- M: MLP. 64-row tiles, 512 threads, grid (8,128) ----------------
__global__ __launch_bounds__(512, 4) void mlp_kernel(
    const int* __restrict__ lengths,
    const float* __restrict__ b2, const float* __restrict__ W3, const float* __restrict__ b3,
    const unsigned short* __restrict__ w1f, const unsigned short* __restrict__ w2f,
    const float* __restrict__ cc, const float* __restrict__ qinv,
    const float* __restrict__ embout, float* __restrict__ qout) {
  int b = blockIdx.y, lt = blockIdx.x;
  int l0 = lt * 64;
  int t = threadIdx.x;
  int len = lengths[b];
  int nv = len - l0; nv = nv < 0 ? 0 : (nv > 64 ? 64 : nv);

  if (nv == 0) {
    if (t < 64) qout[(size_t)b * 512 + l0 + t] = qinv[b];
    return;
  }

  __shared__ __align__(16) unsigned short h1[64 * 520];
  __shared__ float qpart[8][64];
  int w = t >> 6, l = t & 63, g = l >> 4, ln = l & 15;

  // ===== S1: H1T[c1][r] = cc[b][c1] + sum_k W1e[k][c1]*emb[r][k]; B-frags direct from global
  f32x4 acc1[4][4];
  #pragma unroll
  for (int mbi = 0; mbi < 4; ++mbi) {
    f32x4 ccv = *(const f32x4*)(cc + (size_t)b * 512 + (w * 4 + mbi) * 16 + g * 4);
    #pragma unroll
    for (int nb = 0; nb < 4; ++nb) acc1[mbi][nb] = ccv;
  }
  const float* eb = embout + (size_t)(b * 512 + l0) * 128;
  #pragma unroll
  for (int ks = 0; ks < 4; ++ks) {
    short8_t bfr[4];
    #pragma unroll
    for (int nb = 0; nb < 4; ++nb) {
      int r = nb * 16 + ln;
      f32x4 v0 = *(const f32x4*)(eb + (size_t)r * 128 + ks * 32 + g * 8);
      f32x4 v1 = *(const f32x4*)(eb + (size_t)r * 128 + ks * 32 + g * 8 + 4);
      short8_t bb;
      bb[0] = (short)f2bf(v0[0]); bb[1] = (short)f2bf(v0[1]);
      bb[2] = (short)f2bf(v0[2]); bb[3] = (short)f2bf(v0[3]);
      bb[4] = (short)f2bf(v1[0]); bb[5] = (short)f2bf(v1[1]);
      bb[6] = (short)f2bf(v1[2]); bb[7] = (short)f2bf(v1[3]);
      bfr[nb] = bb;
    }
    #pragma unroll
    for (int mbi = 0; mbi < 4; ++mbi) {
      short8_t a = *(const short8_t*)(w1f + ((((w * 4 + mbi) * 4 + ks) * 64 + l) << 3));
      #pragma unroll
      for (int nb = 0; nb < 4; ++nb)
        acc1[mbi][nb] = __builtin_amdgcn_mfma_f32_16x16x32_bf16(a, bfr[nb], acc1[mbi][nb], 0, 0, 0);
    }
  }
  // relu + pack H1 bf16 -> LDS
  #pragma unroll
  for (int mbi = 0; mbi < 4; ++mbi) {
    int c0 = (w * 4 + mbi) * 16 + g * 4;
    #pragma unroll
    for (int nb = 0; nb < 4; ++nb) {
      int r = nb * 16 + ln;
      f32x4 v = acc1[mbi][nb];
      short4_t p;
      p[0] = (short)f2bf(fmaxf(v[0], 0.f)); p[1] = (short)f2bf(fmaxf(v[1], 0.f));
      p[2] = (short)f2bf(fmaxf(v[2], 0.f)); p[3] = (short)f2bf(fmaxf(v[3], 0.f));
      *(short4_t*)&h1[r * 520 + c0] = p;
    }
  }
  __syncthreads();

  // ===== S2: H2T[c2][r] = b2[c2] + sum_c1 W2[c1][c2]*H1[r][c1]
  f32x4 acc2[4][4];
  #pragma unroll
  for (int mbi = 0; mbi < 4; ++mbi) {
    f32x4 b2v = *(const f32x4*)(b2 + (w * 4 + mbi) * 16 + g * 4);
    #pragma unroll
    for (int nb = 0; nb < 4; ++nb) acc2[mbi][nb] = b2v;
  }
  #pragma unroll
  for (int ks = 0; ks < 16; ++ks) {
    short8_t bfr[4];
    #pragma unroll
    for (int nb = 0; nb < 4; ++nb)
      bfr[nb] = *(const short8_t*)&h1[(nb * 16 + ln) * 520 + ks * 32 + g * 8];
    #pragma unroll
    for (int mbi = 0; mbi < 4; ++mbi) {
      short8_t a = *(const short8_t*)(w2f + ((((w * 4 + mbi) * 16 + ks) * 64 + l) << 3));
      #pragma unroll
      for (int nb = 0; nb < 4; ++nb)
        acc2[mbi][nb] = __builtin_amdgcn_mfma_f32_16x16x32_bf16(a, bfr[nb], acc2[mbi][nb], 0, 0, 0);
    }
  }

  // ===== S3: q[r] = relu(b3 + sum_c2 relu(H2)*W3)
  float part[4] = {0.f, 0.f, 0.f, 0.f};
  #pragma unroll
  for (int mbi = 0; mbi < 4; ++mbi) {
    int c0 = (w * 4 + mbi) * 16 + g * 4;
    f32x4 w3v = *(const f32x4*)(W3 + c0);
    #pragma unroll
    for (int nb = 0; nb < 4; ++nb) {
      f32x4 v = acc2[mbi][nb];
      part[nb] += fmaxf(v[0], 0.f) * w3v[0] + fmaxf(v[1], 0.f) * w3v[1]
                + fmaxf(v[2], 0.f) * w3v[2] + fmaxf(v[3], 0.f) * w3v[3];
    }
  }
  #pragma unroll
  for (int nb = 0; nb < 4; ++nb) {
    float p = part[nb];
    p += __shfl_xor(p, 16, 64);
    p += __shfl_xor(p, 32, 64);
    if (g == 0) qpart[w][nb * 16 + ln] = p;
  }
  __syncthreads();
  if (t < 64) {
    float q = qpart[0][t] + qpart[1][t] + qpart[2][t] + qpart[3][t]
            + qpart[4][t] + qpart[5][t] + qpart[6][t] + qpart[7][t] + b3[0];
    qout[(size_t)b * 512 + l0 + t] = fmaxf(q, 0.f);
  }
}

extern "C" void kernel_launch(void* const* d_in, const int* in_sizes, int n_in,
                              void* d_out, int out_size, void* d_ws, size_t ws_size,
                              hipStream_t stream) {
  (void)in_sizes; (void)n_in; (void)out_size; (void)ws_size;
  const float* instr  = (const float*)d_in[0];
  const float* state  = (const float*)d_in[1];
  const float* hidden = (const float*)d_in[2];
  const float* adesc  = (const float*)d_in[3];
  const float* astd   = (const float*)d_in[4];
  const int*   tids   = (const int*)d_in[5];
  const int*   lens   = (const int*)d_in[6];
  const float* Wd = (const float*)d_in[7];
  const float* bd = (const float*)d_in[8];
  const float* Ws = (const float*)d_in[9];
  const float* bs = (const float*)d_in[10];
  const float* W1 = (const float*)d_in[11];
  const float* b1 = (const float*)d_in[12];
  const float* W2 = (const float*)d_in[13];
  const float* b2 = (const float*)d_in[14];
  const float* W3 = (const float*)d_in[15];
  const float* b3 = (const float*)d_in[16];

  float* qout = (float*)d_out;
  float* embout = qout + 128 * 512;

  char* ws = (char*)d_ws;
  unsigned short* wdf  = (unsigned short*)(ws);             // 196608 B
  unsigned short* wsf  = (unsigned short*)(ws + 196608);    //  32768 B
  unsigned short* w1f  = (unsigned short*)(ws + 229376);    // 131072 B
  unsigned short* w2f  = (unsigned short*)(ws + 360448);    // 524288 B
  unsigned short* w1cf = (unsigned short*)(ws + 884736);    // 1179648 B
  unsigned short* w2p  = (unsigned short*)(ws + 2064384);   // 524288 B
  unsigned short* ctxb = (unsigned short*)(ws + 2588672);   // 294912 B
  float* cc   = (float*)(ws + 2883584);                     // 262144 B
  float* qinv = (float*)(ws + 3145728);                     // 512 B

  prep_pack<<<512, 256, 0, stream>>>(Wd, Ws, W1, W2, instr, state, hidden,
                                     wdf, wsf, w1f, w2f, w1cf, w2p, ctxb);
  cc_mfma<<<dim3(16, 4), 256, 0, stream>>>(ctxb, w1cf, b1, cc);
  qinv_kernel<<<128, 256, 0, stream>>>(cc, w2p, b2, W3, b3, qinv);
  emb_kernel<<<dim3(16, 128), 256, 0, stream>>>(adesc, astd, tids, lens, bd, bs,
                                                wdf, wsf, embout);
  mlp_kernel<<<dim3(8, 128), 512, 0, stream>>>(lens, b2, W3, b3, w1f, w2f,
                                               cc, qinv, embout, qout);
}

// Round 4
// 153.694 us; speedup vs baseline: 1.6006x; 1.1539x over previous
//
#include <hip/hip_runtime.h>
#include <stdint.h>

// FlatCritic: B=128, L=512, D_DESC=768, D_STD=128, D_ACT=128, D_CTX=1152, H=512
// out = [q (B*L f32), emb (B*L*128 f32)]
//
// v4: restore v1's cheap prologue (fp32 ctx_cc, f32-W2 qinv, small prep);
// emb exports bf16 B-frag-linear embB so mlp S1 does coalesced short8 loads
// instead of strided f32 + f2bf.

typedef __attribute__((ext_vector_type(8))) short short8_t;
typedef __attribute__((ext_vector_type(4))) short short4_t;
typedef __attribute__((ext_vector_type(4))) float f32x4;
typedef __attribute__((ext_vector_type(4))) unsigned int u32x4;

__device__ inline unsigned short f2bf(float f) {
  union { float f; unsigned u; } v; v.f = f;
  unsigned r = v.u + 0x7FFFu + ((v.u >> 16) & 1u);
  return (unsigned short)(r >> 16);
}

// pack W (f32, [K][C] row-major: val(c,k)=src[k*ldc+c]) into MFMA A-frag layout:
// dst[((mb*NKS+ks)*64+lane)*8+j] = bf16( src[(k0+ks*32+(lane>>4)*8+j)*ldc + mb*16+(lane&15)] )
__device__ inline void pack_frags(const float* __restrict__ src, int ldc, int k0, int NKS,
                                  unsigned short* __restrict__ dst, int total, int tid, int n) {
  for (int fi = tid; fi < total; fi += n) {
    int j = fi & 7, lane = (fi >> 3) & 63, rest = fi >> 9;
    int ks = rest % NKS, mb = rest / NKS;
    int c = mb * 16 + (lane & 15);
    int k = k0 + ks * 32 + ((lane >> 4) << 3) + j;
    dst[fi] = f2bf(src[(size_t)k * ldc + c]);
  }
}

__global__ __launch_bounds__(256) void prep_pack(
    const float* __restrict__ Wd, const float* __restrict__ Ws,
    const float* __restrict__ W1, const float* __restrict__ W2,
    unsigned short* __restrict__ wdf, unsigned short* __restrict__ wsf,
    unsigned short* __restrict__ w1f, unsigned short* __restrict__ w2f) {
  int tid = blockIdx.x * 256 + threadIdx.x, n = gridDim.x * 256;
  pack_frags(Wd, 128, 0,    24, wdf,  98304,  tid, n);   // desc proj  [8mb][24ks]
  pack_frags(Ws, 128, 0,    4,  wsf,  16384,  tid, n);   // std proj   [8mb][4ks]
  pack_frags(W1, 512, 1152, 4,  w1f,  65536,  tid, n);   // W1[1152:]  [32mb][4ks]
  pack_frags(W2, 512, 0,    16, w2f,  262144, tid, n);   // W2         [32mb][16ks]
}

// ---------------- cc[b][h] = b1[h] + ctx(b) . W1[:1152, h]  (fp32 exact, v1) ----------------
__global__ __launch_bounds__(256) void ctx_cc(
    const float* __restrict__ instr, const float* __restrict__ state, const float* __restrict__ hidden,
    const float* __restrict__ W1, const float* __restrict__ b1, float* __restrict__ cc) {
  int bid = blockIdx.x;
  int b = bid >> 2, part = bid & 3;
  __shared__ float ctx[1152];
  __shared__ float red[256];
  int t = threadIdx.x;
  for (int i = t; i < 512; i += 256) { ctx[i] = instr[b * 512 + i]; ctx[512 + i] = state[b * 512 + i]; }
  if (t < 128) ctx[1024 + t] = hidden[b * 128 + t];
  __syncthreads();
  int hcol = part * 128 + (t & 127);
  int half = t >> 7;
  float acc = 0.f;
  const float* wp = W1 + (size_t)half * 576 * 512 + hcol;
  #pragma unroll 8
  for (int d = 0; d < 576; ++d) acc = fmaf(ctx[half * 576 + d], wp[(size_t)d * 512], acc);
  red[t] = acc;
  __syncthreads();
  if (t < 128) cc[b * 512 + hcol] = red[t] + red[t + 128] + b1[hcol];
}

// ---------------- q_inv[b]: MLP tail on emb=0 rows (f32 W2, v1) ----------------
__global__ __launch_bounds__(256) void qinv_kernel(
    const float* __restrict__ cc, const float* __restrict__ W2, const float* __restrict__ b2,
    const float* __restrict__ W3, const float* __restrict__ b3, float* __restrict__ qinv) {
  int b = blockIdx.x, t = threadIdx.x;
  __shared__ float h1s[512];
  __shared__ float red[256];
  for (int i = t; i < 512; i += 256) h1s[i] = fmaxf(cc[b * 512 + i], 0.f);
  __syncthreads();
  float a0 = b2[t], a1 = b2[t + 256];
  #pragma unroll 4
  for (int c = 0; c < 512; ++c) {
    float x = h1s[c];
    a0 = fmaf(x, W2[(size_t)c * 512 + t], a0);
    a1 = fmaf(x, W2[(size_t)c * 512 + t + 256], a1);
  }
  red[t] = fmaxf(a0, 0.f) * W3[t] + fmaxf(a1, 0.f) * W3[t + 256];
  __syncthreads();
  for (int s = 128; s > 0; s >>= 1) { if (t < s) red[t] += red[t + s]; __syncthreads(); }
  if (t == 0) qinv[b] = fmaxf(red[0] + b3[0], 0.f);
}

// ---------------- E: emb producer. 32-row tiles, 256 threads, grid (16,128) ----------------
// outputs: embout f32 (final output) + embB bf16 in B-frag-linear layout:
// embB[(((tile*4+ks)*2+nb)*64 + lane)*8 + j] = bf16emb[r=nb*16+(lane&15)][k=ks*32+(lane>>4)*8+j]
__global__ __launch_bounds__(256, 4) void emb_kernel(
    const float* __restrict__ adesc, const float* __restrict__ astd,
    const int* __restrict__ type_ids, const int* __restrict__ lengths,
    const float* __restrict__ bdesc, const float* __restrict__ bstd,
    const unsigned short* __restrict__ wdf, const unsigned short* __restrict__ wsf,
    float* __restrict__ embout, unsigned short* __restrict__ embB) {
  int b = blockIdx.y, lt = blockIdx.x;
  int l0 = lt * 32;
  int t = threadIdx.x;
  int tile = b * 16 + lt;
  int len = lengths[b];
  int nv = len - l0; nv = nv < 0 ? 0 : (nv > 32 ? 32 : nv);
  f32x4 zero4 = {0.f, 0.f, 0.f, 0.f};

  if (nv == 0) {  // fully-invalid tile: emb = 0, embB = 0 (q handled by M)
    float* ep = embout + (size_t)(b * 512 + l0) * 128;
    #pragma unroll
    for (int i = 0; i < 4; ++i) ((f32x4*)ep)[t + i * 256] = zero4;
    u32x4 z4 = {0u, 0u, 0u, 0u};
    u32x4* bp = (u32x4*)(embB + (size_t)tile * 4096);
    bp[t] = z4; bp[t + 256] = z4;
    return;
  }

  __shared__ __align__(16) unsigned short act[2][32 * 136];
  __shared__ int typeL[32];
  int w = t >> 6, l = t & 63, g = l >> 4, ln = l & 15;

  if (t < 32) typeL[t] = type_ids[b * 512 + l0 + t];

  const float* descB = adesc + (size_t)(b * 512 + l0) * 768;
  const float* stdB  = astd  + (size_t)(b * 512 + l0) * 128;

  __syncthreads();  // typeL ready

  // reg-split staging (T14): issue -> [MFMA prev] -> write
  f32x4 stg[4];
  int r0 = t >> 5, c4 = t & 31;

  auto issue = [&](int kc) {
    bool isStd = (kc == 6);
    #pragma unroll
    for (int i = 0; i < 4; ++i) {
      int r = r0 + i * 8;
      bool ok = (r < nv) && ((typeL[r] == 0) != isStd);
      f32x4 v = zero4;
      if (ok) v = isStd ? *(const f32x4*)(stdB + (size_t)r * 128 + c4 * 4)
                        : *(const f32x4*)(descB + (size_t)r * 768 + kc * 128 + c4 * 4);
      stg[i] = v;
    }
  };
  auto writebuf = [&](int kc) {
    unsigned short* buf = act[kc & 1];
    #pragma unroll
    for (int i = 0; i < 4; ++i) {
      short4_t p;
      p[0] = (short)f2bf(stg[i][0]); p[1] = (short)f2bf(stg[i][1]);
      p[2] = (short)f2bf(stg[i][2]); p[3] = (short)f2bf(stg[i][3]);
      *(short4_t*)&buf[(r0 + i * 8) * 136 + c4 * 4] = p;
    }
  };

  issue(0); writebuf(0);

  f32x4 acc[2][2];
  #pragma unroll
  for (int mb = 0; mb < 2; ++mb)
    #pragma unroll
    for (int nb = 0; nb < 2; ++nb) acc[mb][nb] = zero4;

  for (int kc = 0; kc < 7; ++kc) {
    __syncthreads();  // buf[kc&1] writes visible; all prev reads of buf[(kc+1)&1] done
    if (kc < 6) issue(kc + 1);
    const unsigned short* buf = act[kc & 1];
    bool isStd = (kc == 6);
    #pragma unroll
    for (int ks = 0; ks < 4; ++ks) {
      short8_t bfr[2];
      #pragma unroll
      for (int nb = 0; nb < 2; ++nb)
        bfr[nb] = *(const short8_t*)&buf[(nb * 16 + ln) * 136 + ks * 32 + g * 8];
      #pragma unroll
      for (int mb = 0; mb < 2; ++mb) {
        const unsigned short* ap = isStd ? (wsf + ((((w * 2 + mb) * 4 + ks) * 64 + l) << 3))
                                         : (wdf + ((((w * 2 + mb) * 24 + kc * 4 + ks) * 64 + l) << 3));
        short8_t a = *(const short8_t*)ap;
        #pragma unroll
        for (int nb = 0; nb < 2; ++nb)
          acc[mb][nb] = __builtin_amdgcn_mfma_f32_16x16x32_bf16(a, bfr[nb], acc[mb][nb], 0, 0, 0);
      }
    }
    if (kc < 6) writebuf(kc + 1);
  }
  __syncthreads();  // last MFMAs done reading act[0] -> reuse as E

  // epilogue: masked bias + f32 global store + bf16 -> E (act[0], [32][136])
  unsigned short* E = act[0];
  #pragma unroll
  for (int mb = 0; mb < 2; ++mb) {
    int k0 = w * 32 + mb * 16 + g * 4;
    f32x4 bd4 = *(const f32x4*)(bdesc + k0);
    f32x4 bs4 = *(const f32x4*)(bstd + k0);
    #pragma unroll
    for (int nb = 0; nb < 2; ++nb) {
      int r = nb * 16 + ln;
      f32x4 e = acc[mb][nb];
      if (r < nv) { f32x4 bias = (typeL[r] == 0) ? bd4 : bs4; e = e + bias; }
      else e = zero4;
      *(f32x4*)(embout + (size_t)(b * 512 + l0 + r) * 128 + k0) = e;
      short4_t p; p[0] = (short)f2bf(e[0]); p[1] = (short)f2bf(e[1]);
      p[2] = (short)f2bf(e[2]); p[3] = (short)f2bf(e[3]);
      *(short4_t*)&E[r * 136 + k0] = p;
    }
  }
  __syncthreads();

  // export B-frag-linear embB (coalesced 1KB stores)
  unsigned short* bbase = embB + (size_t)tile * 4096;
  #pragma unroll
  for (int ks = 0; ks < 4; ++ks)
    #pragma unroll
    for (int nb = 0; nb < 2; ++nb) {
      short8_t v = *(const short8_t*)&E[(nb * 16 + ln) * 136 + ks * 32 + g * 8];
      *(short8_t*)&bbase[((ks * 2 + nb) * 64 + l) * 8] = v;
    }
}

// ---------------- M: MLP. 64-row tiles, 512 threads, grid (8,128) ----------------
__global__ __launch_bounds__(512, 4) void mlp_kernel(
    const int* __restrict__ lengths,
    const float* __restrict__ b2, const float* __restrict__ W3, const float* __restrict__ b3,
    const unsigned short* __restrict__ w1f, const unsigned short* __restrict__ w2f,
    const float* __restrict__ cc, const float* __restrict__ qinv,
    const unsigned short* __restrict__ embB, float* __restrict__ qout) {
  int b = blockIdx.y, lt = blockIdx.x;
  int l0 = lt * 64;
  int t = threadIdx.x;
  int len = lengths[b];
  int nv = len - l0; nv = nv < 0 ? 0 : (nv > 64 ? 64 : nv);

  if (nv == 0) {
    if (t < 64) qout[(size_t)b * 512 + l0 + t] = qinv[b];
    return;
  }

  __shared__ __align__(16) unsigned short h1[64 * 520];
  __shared__ float qpart[8][64];
  int w = t >> 6, l = t & 63, g = l >> 4, ln = l & 15;

  // ===== S1: H1T[c1][r] = cc[b][c1] + sum_k W1e[k][c1]*emb[r][k]; B-frags from embB
  f32x4 acc1[4][4];
  #pragma unroll
  for (int mbi = 0; mbi < 4; ++mbi) {
    f32x4 ccv = *(const f32x4*)(cc + (size_t)b * 512 + (w * 4 + mbi) * 16 + g * 4);
    #pragma unroll
    for (int nb = 0; nb < 4; ++nb) acc1[mbi][nb] = ccv;
  }
  const unsigned short* ebase = embB + (size_t)(b * 16 + lt * 2) * 4096;  // two 32-row half-tiles
  #pragma unroll
  for (int ks = 0; ks < 4; ++ks) {
    short8_t bfr[4];
    #pragma unroll
    for (int nb = 0; nb < 4; ++nb) {
      // half-tile h = nb>>1 (offset h*4096), local nb&1
      bfr[nb] = *(const short8_t*)&ebase[(nb >> 1) * 4096 + ((ks * 2 + (nb & 1)) * 64 + l) * 8];
    }
    #pragma unroll
    for (int mbi = 0; mbi < 4; ++mbi) {
      short8_t a = *(const short8_t*)(w1f + ((((w * 4 + mbi) * 4 + ks) * 64 + l) << 3));
      #pragma unroll
      for (int nb = 0; nb < 4; ++nb)
        acc1[mbi][nb] = __builtin_amdgcn_mfma_f32_16x16x32_bf16(a, bfr[nb], acc1[mbi][nb], 0, 0, 0);
    }
  }
  // relu + pack H1 bf16 -> LDS
  #pragma unroll
  for (int mbi = 0; mbi < 4; ++mbi) {
    int c0 = (w * 4 + mbi) * 16 + g * 4;
    #pragma unroll
    for (int nb = 0; nb < 4; ++nb) {
      int r = nb * 16 + ln;
      f32x4 v = acc1[mbi][nb];
      short4_t p;
      p[0] = (short)f2bf(fmaxf(v[0], 0.f)); p[1] = (short)f2bf(fmaxf(v[1], 0.f));
      p[2] = (short)f2bf(fmaxf(v[2], 0.f)); p[3] = (short)f2bf(fmaxf(v[3], 0.f));
      *(short4_t*)&h1[r * 520 + c0] = p;
    }
  }
  __syncthreads();

  // ===== S2: H2T[c2][r] = b2[c2] + sum_c1 W2[c1][c2]*H1[r][c1]
  f32x4 acc2[4][4];
  #pragma unroll
  for (int mbi = 0; mbi < 4; ++mbi) {
    f32x4 b2v = *(const f32x4*)(b2 + (w * 4 + mbi) * 16 + g * 4);
    #pragma unroll
    for (int nb = 0; nb < 4; ++nb) acc2[mbi][nb] = b2v;
  }
  #pragma unroll
  for (int ks = 0; ks < 16; ++ks) {
    short8_t bfr[4];
    #pragma unroll
    for (int nb = 0; nb < 4; ++nb)
      bfr[nb] = *(const short8_t*)&h1[(nb * 16 + ln) * 520 + ks * 32 + g * 8];
    #pragma unroll
    for (int mbi = 0; mbi < 4; ++mbi) {
      short8_t a = *(const short8_t*)(w2f + ((((w * 4 + mbi) * 16 + ks) * 64 + l) << 3));
      #pragma unroll
      for (int nb = 0; nb < 4; ++nb)
        acc2[mbi][nb] = __builtin_amdgcn_mfma_f32_16x16x32_bf16(a, bfr[nb], acc2[mbi][nb], 0, 0, 0);
    }
  }

  // ===== S3: q[r] = relu(b3 + sum_c2 relu(H2)*W3)
  float part[4] = {0.f, 0.f, 0.f, 0.f};
  #pragma unroll
  for (int mbi = 0; mbi < 4; ++mbi) {
    int c0 = (w * 4 + mbi) * 16 + g * 4;
    f32x4 w3v = *(const f32x4*)(W3 + c0);
    #pragma unroll
    for (int nb = 0; nb < 4; ++nb) {
      f32x4 v = acc2[mbi][nb];
      part[nb] += fmaxf(v[0], 0.f) * w3v[0] + fmaxf(v[1], 0.f) * w3v[1]
                + fmaxf(v[2], 0.f) * w3v[2] + fmaxf(v[3], 0.f) * w3v[3];
    }
  }
  #pragma unroll
  for (int nb = 0; nb < 4; ++nb) {
    float p = part[nb];
    p += __shfl_xor(p, 16, 64);
    p += __shfl_xor(p, 32, 64);
    if (g == 0) qpart[w][nb * 16 + ln] = p;
  }
  __syncthreads();
  if (t < 64) {
    float q = qpart[0][t] + qpart[1][t] + qpart[2][t] + qpart[3][t]
            + qpart[4][t] + qpart[5][t] + qpart[6][t] + qpart[7][t] + b3[0];
    qout[(size_t)b * 512 + l0 + t] = fmaxf(q, 0.f);
  }
}

extern "C" void kernel_launch(void* const* d_in, const int* in_sizes, int n_in,
                              void* d_out, int out_size, void* d_ws, size_t ws_size,
                              hipStream_t stream) {
  (void)in_sizes; (void)n_in; (void)out_size; (void)ws_size;
  const float* instr  = (const float*)d_in[0];
  const float* state  = (const float*)d_in[1];
  const float* hidden = (const float*)d_in[2];
  const float* adesc  = (const float*)d_in[3];
  const float* astd   = (const float*)d_in[4];
  const int*   tids   = (const int*)d_in[5];
  const int*   lens   = (const int*)d_in[6];
  const float* Wd = (const float*)d_in[7];
  const float* bd = (const float*)d_in[8];
  const float* Ws = (const float*)d_in[9];
  const float* bs = (const float*)d_in[10];
  const float* W1 = (const float*)d_in[11];
  const float* b1 = (const float*)d_in[12];
  const float* W2 = (const float*)d_in[13];
  const float* b2 = (const float*)d_in[14];
  const float* W3 = (const float*)d_in[15];
  const float* b3 = (const float*)d_in[16];

  float* qout = (float*)d_out;
  float* embout = qout + 128 * 512;

  char* ws = (char*)d_ws;
  unsigned short* wdf  = (unsigned short*)(ws);             // 196608 B
  unsigned short* wsf  = (unsigned short*)(ws + 196608);    //  32768 B
  unsigned short* w1f  = (unsigned short*)(ws + 229376);    // 131072 B
  unsigned short* w2f  = (unsigned short*)(ws + 360448);    // 524288 B
  float* cc   = (float*)(ws + 884736);                      // 262144 B
  float* qinv = (float*)(ws + 1146880);                     // 512 B
  unsigned short* embB = (unsigned short*)(ws + 1147392);   // 16777216 B

  prep_pack<<<256, 256, 0, stream>>>(Wd, Ws, W1, W2, wdf, wsf, w1f, w2f);
  ctx_cc<<<512, 256, 0, stream>>>(instr, state, hidden, W1, b1, cc);
  qinv_kernel<<<128, 256, 0, stream>>>(cc, W2, b2, W3, b3, qinv);
  emb_kernel<<<dim3(16, 128), 256, 0, stream>>>(adesc, astd, tids, lens, bd, bs,
                                                wdf, wsf, embout, embB);
  mlp_kernel<<<dim3(8, 128), 512, 0, stream>>>(lens, b2, W3, b3, w1f, w2f,
                                               cc, qinv, embB, qout);
}